// Round 1
// 994.087 us; speedup vs baseline: 1.0534x; 1.0534x over previous
//
#include <hip/hip_runtime.h>
#include <cstdint>
#include <cstddef>

// ---------------------------------------------------------------------------
// TemperGraph on gfx950 — R5: R4's fp16x2 MFMA GEMMs restructured into a
// double-buffered 2-phase pipeline (T3/T4: counted vmcnt + raw s_barrier,
// never vmcnt(0) in steady state) + XCD-chunked block swizzle (T1) +
// setprio around MFMA (T5). k_routemm gets the same pipeline.
// FP ordering is bitwise identical to R4 (same tile order / MFMA sequence).
// Exact JAX threefry sampling preserved (passed R1-R4).
// ---------------------------------------------------------------------------

#define NPATCH 32768          // B(2048) * num_patches(16)
#define NHOP 4
#define RSCALE 4096.0f
#define RINV   2.44140625e-4f  // 2^-12

typedef unsigned short u16;
typedef __attribute__((ext_vector_type(8))) _Float16 half8;  // 8 f16 (4 VGPRs)
typedef __attribute__((ext_vector_type(4))) float f32x4;

#define GLDS(gp, lp) __builtin_amdgcn_global_load_lds( \
    (const __attribute__((address_space(1))) void*)(const void*)(gp), \
    (__attribute__((address_space(3))) void*)(void*)(lp), 16, 0, 0)

// ------------------------------- threefry ----------------------------------
__device__ __forceinline__ uint32_t rotl32(uint32_t x, int r){ return (x<<r)|(x>>(32-r)); }

__device__ __forceinline__ void tf2x32(uint32_t k0, uint32_t k1, uint32_t x0, uint32_t x1,
                                       uint32_t& o0, uint32_t& o1){
  uint32_t k2 = k0 ^ k1 ^ 0x1BD11BDAu;
  x0 += k0; x1 += k1;
#define TFR(r) { x0 += x1; x1 = rotl32(x1,(r)); x1 ^= x0; }
  TFR(13) TFR(15) TFR(26) TFR(6)   x0 += k1; x1 += k2 + 1u;
  TFR(17) TFR(29) TFR(16) TFR(24)  x0 += k2; x1 += k0 + 2u;
  TFR(13) TFR(15) TFR(26) TFR(6)   x0 += k0; x1 += k1 + 3u;
  TFR(17) TFR(29) TFR(16) TFR(24)  x0 += k1; x1 += k2 + 4u;
  TFR(13) TFR(15) TFR(26) TFR(6)   x0 += k2; x1 += k0 + 5u;
#undef TFR
  o0 = x0; o1 = x1;
}

__device__ __forceinline__ uint32_t jbits32(uint32_t k0, uint32_t k1, uint32_t idx){
  uint32_t a, b; tf2x32(k0, k1, 0u, idx, a, b);
  return a ^ b;
}

__device__ __forceinline__ void jsplit(uint32_t& r0, uint32_t& r1, uint32_t& c0, uint32_t& c1){
  uint32_t n0, n1;
  tf2x32(r0, r1, 0u, 0u, n0, n1);
  tf2x32(r0, r1, 0u, 1u, c0, c1);
  r0 = n0; r1 = n1;
}

__device__ __forceinline__ float jgumbel(uint32_t bits){
  float f = __uint_as_float(0x3f800000u | (bits >> 9)) - 1.0f;
  float u = fmaxf(f, 1.17549435e-38f);
  return -logf(-logf(u));
}

// ------------------------------- fp16 split helpers ------------------------
union uhcv { _Float16 h; u16 u; };
__device__ __forceinline__ u16 f2h(float x){ uhcv t; t.h = (_Float16)x; return t.u; }
__device__ __forceinline__ float h2f(u16 b){ uhcv t; t.u = b; return (float)t.h; }
__device__ __forceinline__ void split2s(float v, u16& a0, u16& a1){
  a0 = f2h(v);
  a1 = f2h((v - h2f(a0)) * RSCALE);
}

// ------------------------------- key derivation ----------------------------
__global__ void k_keys(const int* __restrict__ seed, const float* __restrict__ op_logits,
                       uint32_t* __restrict__ keys, float* __restrict__ logp3){
  if (threadIdx.x != 0 || blockIdx.x != 0) return;
  uint32_t r0 = 0u, r1 = (uint32_t)seed[0];
  uint32_t c0, c1;
  jsplit(r0, r1, c0, c1); keys[0] = c0; keys[1] = c1;          // tk
  for (int h = 0; h < NHOP; h++){
    jsplit(r0, r1, c0, c1); keys[2 + 4*h] = c0; keys[3 + 4*h] = c1;  // ok_h
    jsplit(r0, r1, c0, c1); keys[4 + 4*h] = c0; keys[5 + 4*h] = c1;  // sk_h
  }
  float l0 = op_logits[0], l1 = op_logits[1], l2 = op_logits[2];
  float mm = fmaxf(l0, fmaxf(l1, l2));
  float e0 = expf(l0-mm), e1 = expf(l1-mm), e2 = expf(l2-mm);
  float ssum = e0 + e1 + e2;
  logp3[0] = logf(e0/ssum); logp3[1] = logf(e1/ssum); logp3[2] = logf(e2/ssum);
}

// ------------------------------- init --------------------------------------
__global__ __launch_bounds__(256)
void k_init(const uint32_t* __restrict__ keys, int* __restrict__ tempers, int* __restrict__ done){
  int i = blockIdx.x*256 + threadIdx.x;
  uint32_t b = jbits32(keys[0], keys[1], (uint32_t)(NPATCH + i));
  tempers[i] = (int)(b & 63u);
  done[i] = 0;
}

// ------------------------------- precompute --------------------------------
__global__ __launch_bounds__(256)
void k_precomp(const float* __restrict__ id_embeds, const float* __restrict__ op_emb,
               const float* __restrict__ tid_emb,
               const float* __restrict__ W1, const float* __restrict__ b1,
               const float* __restrict__ Wr1, const float* __restrict__ br1,
               float* __restrict__ idW, float* __restrict__ opWb, float* __restrict__ tidWb){
  int b = blockIdx.x, tid = threadIdx.x;
  if (b < 64){
    for (int j = tid; j < 512; j += 256){
      float v = 0.f;
      #pragma unroll
      for (int u = 0; u < 4; u++) v = fmaf(id_embeds[b*4+u], W1[(size_t)(512+u)*512 + j], v);
      idW[b*512 + j] = v;
    }
  } else if (b < 67){
    int o = b - 64;
    for (int j = tid; j < 512; j += 256){
      float v = b1[j];
      for (int u = 0; u < 256; u++) v = fmaf(op_emb[o*256+u], W1[(size_t)(516+u)*512 + j], v);
      opWb[o*512 + j] = v;
    }
  } else {
    for (int idx = tid; idx < 2048; idx += 256){
      int t = idx >> 5, c = idx & 31;
      float v = br1[c];
      #pragma unroll
      for (int u = 0; u < 4; u++) v = fmaf(tid_emb[t*4+u], Wr1[(512+u)*32 + c], v);
      tidWb[idx] = v;
    }
  }
}

// ------------------------------- weight transpose + split ------------------
// W1T/W2T: 2 fp16 planes [512][512] (k contig). Wr1P: 2 planes [32][512].
// WpT: 1 plane [8192][512].
__global__ __launch_bounds__(256)
void k_splitW(const float* __restrict__ W1, const float* __restrict__ W2,
              const float* __restrict__ Wp, const float* __restrict__ Wr1,
              u16* __restrict__ W1T, u16* __restrict__ W2T, u16* __restrict__ WpT,
              u16* __restrict__ Wr1P){
  __shared__ float t[32][33];
  int blk = blockIdx.x;
  const float* src; u16* dst; int N; int deg; size_t pst; int tb;
  if (blk < 256){ src = W1; dst = W1T; N = 512; deg = 2; pst = (size_t)512*512; tb = blk; }
  else if (blk < 512){ src = W2; dst = W2T; N = 512; deg = 2; pst = (size_t)512*512; tb = blk - 256; }
  else if (blk < 528){ src = Wr1; dst = Wr1P; N = 32; deg = 2; pst = (size_t)32*512; tb = blk - 512; }
  else { src = Wp; dst = WpT; N = 8192; deg = 1; pst = 0; tb = blk - 528; }
  int n0 = (tb >> 4)*32, k0 = (tb & 15)*32;
  if (N == 32){ n0 = 0; k0 = tb*32; }
  int r = threadIdx.x >> 5, c = threadIdx.x & 31;
  for (int rr = r; rr < 32; rr += 8)
    t[rr][c] = src[(size_t)(k0+rr)*N + ((n0 + c) % N)];
  __syncthreads();
  for (int rr = r; rr < 32; rr += 8){
    if (n0 + rr >= N) break;
    float v = t[c][rr];                       // src[k0+c][n0+rr]
    size_t o = (size_t)(n0+rr)*512 + k0 + c;
    if (deg == 2){
      u16 a0, a1; split2s(v, a0, a1);
      dst[o] = a0; dst[pst + o] = a1;
    } else {
      dst[o] = f2h(v);
    }
  }
}

// ------------------------------- x -> states planes ------------------------
__global__ __launch_bounds__(256)
void k_xsplit(const float* __restrict__ x, u16* __restrict__ sP){
  size_t i = ((size_t)blockIdx.x*256 + threadIdx.x)*4;
  float4 v = *(const float4*)(x + i);
  ushort4 p0, p1;
  split2s(v.x, p0.x, p1.x); split2s(v.y, p0.y, p1.y);
  split2s(v.z, p0.z, p1.z); split2s(v.w, p0.w, p1.w);
  const size_t SP = (size_t)NPATCH*512;
  *(ushort4*)(sP + i) = p0; *(ushort4*)(sP + SP + i) = p1;
}

// ------------------------------- active compaction -------------------------
__global__ __launch_bounds__(1024)
void k_scan(const int* __restrict__ done, int* __restrict__ aidx, int* __restrict__ meta){
  __shared__ int cnt[1024];
  int tid = threadIdx.x;
  int base = tid * 32;
  unsigned flags = 0; int c = 0;
  #pragma unroll
  for (int i = 0; i < 32; i++){
    int f = (done[base + i] == 0);
    flags |= ((unsigned)f) << i;
    c += f;
  }
  cnt[tid] = c;
  __syncthreads();
  int val = c;
  for (int off = 1; off < 1024; off <<= 1){
    int v = (tid >= off) ? cnt[tid - off] : 0;
    __syncthreads();
    val += v; cnt[tid] = val;
    __syncthreads();
  }
  int pos = val - c;
  for (int i = 0; i < 32; i++){
    if ((flags >> i) & 1u) aidx[pos++] = base + i;
  }
  __syncthreads();
  int na = cnt[1023];
  for (int j = na + tid; j < NPATCH; j += 1024) aidx[j] = 0;
  if (tid == 0){
    meta[0] = na;
    meta[1] = (na < NPATCH) ? (NPATCH - 1) : 0;
  }
}

// ------------------------------- gather + op sampling ----------------------
__global__ __launch_bounds__(256)
void k_gather(const int* __restrict__ aidx, const int* __restrict__ tempers,
              const uint32_t* __restrict__ keys, const float* __restrict__ logp3,
              int hop, int* __restrict__ t_act, int* __restrict__ op_idx){
  int s = blockIdx.x*256 + threadIdx.x;
  int p = aidx[s];
  t_act[s] = tempers[p];
  uint32_t k0 = keys[2 + 4*hop], k1 = keys[3 + 4*hop];
  float best = 0.f; int bi = 0;
  #pragma unroll
  for (int c = 0; c < 3; c++){
    float v = jgumbel(jbits32(k0, k1, (uint32_t)(3*s + c))) + logp3[c];
    if (c == 0 || v > best){ best = v; bi = c; }
  }
  op_idx[s] = bi;
}

// ------------------------------- fp16x2 MFMA GEMM --------------------------
// MODE 1: A gathered via aidx, + idW[t]+opWb[op], relu, write 2 planes (by s).
// MODE 3: + bias, relu, SCATTER 2 planes to outP[aidx[r]] masked last-wins.
// MODE 2: + bias, write fp32 (DEG=1).
// R5: double-buffered LDS, counted vmcnt (never 0 in steady state),
// raw s_barrier (no compiler drain), setprio around MFMA, XCD block swizzle.
template<int MODE, int DEG>
__global__ __launch_bounds__(256, 2)
void k_mgemm(const u16* __restrict__ Ap, const u16* __restrict__ Bp,
             float* __restrict__ outF, u16* __restrict__ outP,
             const int* __restrict__ aidx, const float* __restrict__ bias,
             const float* __restrict__ idW, const float* __restrict__ opWb,
             const int* __restrict__ t_act, const int* __restrict__ op_idx,
             const int* __restrict__ meta,
             int Ncols, size_t aStride, size_t bStride, size_t oStride){
  __shared__ u16 As[2*DEG*4096];   // [dbuf][plane][128 rows][32 k, 16B-chunk swizzled]
  __shared__ u16 Bs[2*DEG*4096];
  const int tid = threadIdx.x;
  const int L = tid & 63, w = tid >> 6;

  // --- XCD-chunked bijective block swizzle (T1): the col-blocks sharing an
  // A-panel are dispatched consecutively -> land on the SAME XCD's L2.
  const int gx = (int)gridDim.x;
  const int nwg = gx * (int)gridDim.y;
  int lin = (int)blockIdx.y * gx + (int)blockIdx.x;
  if ((nwg & 7) == 0)
    lin = (lin & 7) * (nwg >> 3) + (lin >> 3);
  const int m0 = (lin / gx) * 128, n0 = (lin % gx) * 128;
  const int wr = w >> 1, wc = w & 1;

  constexpr int SPW = DEG*4;
  constexpr int BUFO = DEG*4096;   // u16 elements per LDS buffer
  const bool isA = (w < 2);
  const u16* gB = isA ? Ap : Bp;
  u16* lB = isA ? As : Bs;
  const size_t pstride = isA ? aStride : bStride;
  const u16* gseg[8];
  u16* lseg[8];
  #pragma unroll
  for (int q = 0; q < SPW; q++){
    int ss = (w & 1)*SPW + q;
    int p = ss >> 3, rb = ss & 7;
    int row16 = rb*16 + (L >> 2);
    int grow;
    if (isA) grow = (MODE == 1) ? aidx[m0 + row16] : (m0 + row16);
    else     grow = n0 + row16;
    int swz = (L & 3) ^ ((L >> 2) & 3);
    gseg[q] = gB + p*pstride + (size_t)grow*512 + swz*8;
    lseg[q] = lB + p*4096 + rb*512;
  }

  f32x4 accM[4][4], accR[4][4];
  #pragma unroll
  for (int i = 0; i < 4; i++)
    #pragma unroll
    for (int j = 0; j < 4; j++){ accM[i][j] = (f32x4)0.f; accR[i][j] = (f32x4)0.f; }

  const int rdsw = ((L >> 4) ^ (L & 3))*8;
  const int frow = L & 15;

  // ---- prologue: stage K-tile 0 into buffer 0 ----
  #pragma unroll
  for (int q = 0; q < SPW; q++)
    GLDS(gseg[q], lseg[q]);

  #pragma unroll 2
  for (int kt = 0; kt < 16; kt++){
    const int cb = (kt & 1) * BUFO;
    if (kt < 15){
      const int nb = ((kt + 1) & 1) * BUFO;
      #pragma unroll
      for (int q = 0; q < SPW; q++)
        GLDS(gseg[q] + (kt+1)*32, lseg[q] + nb);
      // wait for OWN current-tile loads only; next tile's SPW stay in flight
      asm volatile("s_waitcnt vmcnt(%0)" :: "n"(SPW) : "memory");
    } else {
      asm volatile("s_waitcnt vmcnt(0)" ::: "memory");
    }
    __builtin_amdgcn_s_barrier();          // all waves' cur-tile LDS valid
    asm volatile("" ::: "memory");

    __builtin_amdgcn_s_setprio(1);
    #pragma unroll
    for (int pa = 0; pa < DEG; pa++){
      half8 af[4];
      #pragma unroll
      for (int i = 0; i < 4; i++)
        af[i] = *(const half8*)&As[cb + pa*4096 + (wr*64 + i*16 + frow)*32 + rdsw];
      #pragma unroll
      for (int pb = 0; pb < DEG - pa; pb++){
        #pragma unroll
        for (int j = 0; j < 4; j++){
          half8 bf = *(const half8*)&Bs[cb + pb*4096 + (wc*64 + j*16 + frow)*32 + rdsw];
          #pragma unroll
          for (int i = 0; i < 4; i++){
            if (pa + pb == 0)
              accM[i][j] = __builtin_amdgcn_mfma_f32_16x16x32_f16(af[i], bf, accM[i][j], 0, 0, 0);
            else
              accR[i][j] = __builtin_amdgcn_mfma_f32_16x16x32_f16(af[i], bf, accR[i][j], 0, 0, 0);
          }
        }
      }
    }
    __builtin_amdgcn_s_setprio(0);

    asm volatile("" ::: "memory");
    __builtin_amdgcn_s_barrier();          // all reads of cur buffer done ->
                                           // next iter may overwrite it
  }

  const int rbase = m0 + wr*64 + (L >> 4)*4;
  const int cbase = n0 + wc*64 + (L & 15);
  const int w0v = (MODE == 3) ? meta[1] : 0;
  #pragma unroll
  for (int i = 0; i < 4; i++){
    #pragma unroll
    for (int reg = 0; reg < 4; reg++){
      int r = rbase + i*16 + reg;
      if (MODE == 1){
        int t = t_act[r], o = op_idx[r];
        #pragma unroll
        for (int j = 0; j < 4; j++){
          int c = cbase + j*16;
          float v = accM[i][j][reg] + RINV*accR[i][j][reg] + idW[t*512 + c] + opWb[o*512 + c];
          v = fmaxf(v, 0.f);
          u16 a0, a1; split2s(v, a0, a1);
          size_t off = (size_t)r*512 + c;
          outP[off] = a0; outP[oStride + off] = a1;
        }
      } else if (MODE == 3){
        int p = aidx[r];
        bool allowed = (p != 0) || (r == w0v);
        #pragma unroll
        for (int j = 0; j < 4; j++){
          int c = cbase + j*16;
          float v = accM[i][j][reg] + RINV*accR[i][j][reg] + bias[c];
          v = fmaxf(v, 0.f);
          if (allowed){
            u16 a0, a1; split2s(v, a0, a1);
            size_t off = (size_t)p*512 + c;
            outP[off] = a0; outP[oStride + off] = a1;
          }
        }
      } else {
        #pragma unroll
        for (int j = 0; j < 4; j++){
          int c = cbase + j*16;
          float v = accM[i][j][reg] + bias[c];
          if (DEG == 2) v += RINV*accR[i][j][reg];
          outF[(size_t)r*Ncols + c] = v;
        }
      }
    }
  }
}

// ------------------------------- routing matvec via MFMA -------------------
// l32[s][c] = relu( statesP[aidx[s]] . Wr1P[c] + tidWb[t_act[s]][c] )
// 64 rows/block, 4 waves x 16 rows; fp16x2 3-term. R5: same 2-phase pipeline.
__global__ __launch_bounds__(256, 2)
void k_routemm(const u16* __restrict__ sP, const u16* __restrict__ Wr1P,
               const int* __restrict__ aidx, const int* __restrict__ t_act,
               const float* __restrict__ tidWb, float* __restrict__ l32g){
  __shared__ u16 As[2*2*2048];   // [dbuf][plane][64 rows][32 k swizzled]
  __shared__ u16 Bs[2*2048];     // [dbuf][p][ct][q4][nn][8]
  const int tid = threadIdx.x;
  const int L = tid & 63, w = tid >> 6;
  const int m0 = blockIdx.x*64;
  const size_t SPh = (size_t)NPATCH*512;

  const u16* gseg[2]; u16* lseg[2];
  #pragma unroll
  for (int q = 0; q < 2; q++){
    int ss = w*2 + q;
    int p = ss >> 2, rb = ss & 3;
    int row16 = rb*16 + (L >> 2);
    int grow = aidx[m0 + row16];
    int swz = (L & 3) ^ ((L >> 2) & 3);
    gseg[q] = sP + p*SPh + (size_t)grow*512 + swz*8;
    lseg[q] = As + p*2048 + rb*512;
  }
  const u16* gBp = Wr1P + (size_t)(tid>>7)*16384
                        + (size_t)(((tid>>6)&1)*16 + (tid&15))*512 + ((tid>>4)&3)*8;
  u16* lBp = Bs + w*512;

  f32x4 accM[2], accR[2];
  accM[0] = (f32x4)0.f; accM[1] = (f32x4)0.f;
  accR[0] = (f32x4)0.f; accR[1] = (f32x4)0.f;

  const int rdsw = ((L >> 4) ^ (L & 3))*8;

  // ---- prologue: stage K-tile 0 into buffer 0 ----
  #pragma unroll
  for (int q = 0; q < 2; q++) GLDS(gseg[q], lseg[q]);
  GLDS(gBp, lBp);

  #pragma unroll 2
  for (int kt = 0; kt < 16; kt++){
    const int cb  = (kt & 1) * 4096;
    const int cbB = (kt & 1) * 2048;
    if (kt < 15){
      const int nb  = ((kt + 1) & 1) * 4096;
      const int nbB = ((kt + 1) & 1) * 2048;
      #pragma unroll
      for (int q = 0; q < 2; q++)
        GLDS(gseg[q] + (kt+1)*32, lseg[q] + nb);
      GLDS(gBp + (kt+1)*32, lBp + nbB);
      asm volatile("s_waitcnt vmcnt(3)" ::: "memory");
    } else {
      asm volatile("s_waitcnt vmcnt(0)" ::: "memory");
    }
    __builtin_amdgcn_s_barrier();
    asm volatile("" ::: "memory");

    #pragma unroll
    for (int pa = 0; pa < 2; pa++){
      half8 af = *(const half8*)&As[cb + pa*2048 + (w*16 + (L & 15))*32 + rdsw];
      #pragma unroll
      for (int pb = 0; pb < 2 - pa; pb++){
        #pragma unroll
        for (int ct = 0; ct < 2; ct++){
          half8 bf = *(const half8*)&Bs[cbB + (pb*2 + ct)*512 + (L >> 4)*128 + (L & 15)*8];
          if (pa + pb == 0)
            accM[ct] = __builtin_amdgcn_mfma_f32_16x16x32_f16(af, bf, accM[ct], 0, 0, 0);
          else
            accR[ct] = __builtin_amdgcn_mfma_f32_16x16x32_f16(af, bf, accR[ct], 0, 0, 0);
        }
      }
    }

    asm volatile("" ::: "memory");
    __builtin_amdgcn_s_barrier();
  }

  #pragma unroll
  for (int reg = 0; reg < 4; reg++){
    int s = m0 + w*16 + (L >> 4)*4 + reg;
    int t = t_act[s];
    #pragma unroll
    for (int ct = 0; ct < 2; ct++){
      int c = ct*16 + (L & 15);
      float v = accM[ct][reg] + RINV*accR[ct][reg] + tidWb[t*32 + c];
      l32g[(size_t)s*32 + c] = fmaxf(v, 0.f);
    }
  }
}

// ------------------------------- sampling ----------------------------------
__global__ __launch_bounds__(256)
void k_sample(const float* __restrict__ l32g, const float* __restrict__ Wr2,
              const float* __restrict__ br2,
              const int* __restrict__ aidx, const int* __restrict__ meta,
              const uint32_t* __restrict__ keys, int hop,
              int* __restrict__ tempers, int* __restrict__ done){
  __shared__ float l32s[8][32];
  const int tid = threadIdx.x;
  const int s0 = blockIdx.x * 8;
  l32s[tid >> 5][tid & 31] = l32g[(size_t)s0*32 + tid];
  __syncthreads();

  const int lane = tid & 63, w = tid >> 6;
  const int half = lane >> 5;
  const uint32_t sk0 = keys[4 + 4*hop], sk1 = keys[5 + 4*hop];
  int smp[2];
  for (int pass = 0; pass < 2; pass++){
    const int psl = w*2 + pass;
    const int ps  = s0 + psl;
    const int c = lane;
    float lg = br2[c];
    #pragma unroll
    for (int k = 0; k < 32; k++) lg = fmaf(l32s[psl][k], Wr2[k*65 + c], lg);
    float lg64 = br2[64];
    #pragma unroll
    for (int k = 0; k < 32; k++) lg64 = fmaf(l32s[psl][k], Wr2[k*65 + 64], lg64);
    float m = lg;
    for (int off = 32; off; off >>= 1) m = fmaxf(m, __shfl_xor(m, off));
    m = fmaxf(m, lg64);
    float se = expf(lg - m);
    for (int off = 32; off; off >>= 1) se += __shfl_xor(se, off);
    se += expf(lg64 - m);
    float Lse = logf(se);
    float g = jgumbel(jbits32(sk0, sk1, (uint32_t)(65*ps + c)));
    float v = (lg - m) - Lse + g;
    int idx = c;
    for (int off = 32; off; off >>= 1){
      float ov = __shfl_xor(v, off);
      int   oi = __shfl_xor(idx, off);
      if (ov > v || (ov == v && oi < idx)){ v = ov; idx = oi; }
    }
    float g64 = jgumbel(jbits32(sk0, sk1, (uint32_t)(65*ps + 64)));
    float v64 = (lg64 - m) - Lse + g64;
    if (v64 > v) idx = 64;
    smp[pass] = idx;
  }

  const int s = s0 + w*2 + half;
  const int mysmp = smp[half];
  const int p = aidx[s];
  const bool allowed = (p != 0) || (s == meta[1]);
  if (allowed && (lane & 31) == 0){
    tempers[p] = (mysmp < 63) ? mysmp : 63;
    done[p]    = (mysmp == 64) ? 1 : 0;
  }
}

// ------------------------------- latent (mean over patches) ----------------
__global__ __launch_bounds__(256)
void k_latent2(const u16* __restrict__ sP, float* __restrict__ outF, u16* __restrict__ latP){
  int idx = blockIdx.x*256 + threadIdx.x;       // < 2048*512
  int b = idx >> 9, j = idx & 511;
  const size_t SP = (size_t)NPATCH*512;
  float s = 0.f;
  #pragma unroll 4
  for (int u = 0; u < 16; u++){
    size_t e = (size_t)(b*16 + u)*512 + j;
    s += h2f(sP[e]) + RINV*h2f(sP[SP + e]);
  }
  s *= 0.0625f;
  outF[idx] = s;
  latP[idx] = f2h(s);
}

// ===========================================================================
// ------------- R1 fallback pipeline (fp32 VALU GEMM), verbatim -------------
// ===========================================================================
template<int MODE>
__global__ __launch_bounds__(256)
void k_gemmF(const float* __restrict__ A, const float* __restrict__ B, float* __restrict__ C,
             int Ncols,
             const int* __restrict__ aidx,
             const float* __restrict__ bias,
             const float* __restrict__ idW, const float* __restrict__ opWb,
             const int* __restrict__ t_act, const int* __restrict__ op_idx){
  __shared__ float As[16][128];
  __shared__ float Bs[16][128];
  const int tid = threadIdx.x;
  const int bx = blockIdx.x, by = blockIdx.y;
  const int tx = tid & 15, ty = tid >> 4;
  const int lr = tid >> 1, lhalf = tid & 1;
  const int srow = by*128 + lr;
  const int arow = (MODE == 1) ? aidx[srow] : srow;
  const float* Ap = A + (size_t)arow*512 + lhalf*8;
  const float* Bp = B + (size_t)(tid >> 4)*Ncols + bx*128 + (tid & 15)*8;

  float acc[8][8];
  #pragma unroll
  for (int i = 0; i < 8; i++)
    #pragma unroll
    for (int j = 0; j < 8; j++) acc[i][j] = 0.f;

  for (int kt = 0; kt < 512; kt += 16){
    float4 a0 = *(const float4*)(Ap + kt);
    float4 a1 = *(const float4*)(Ap + kt + 4);
    float4 g0 = *(const float4*)(Bp + (size_t)kt*Ncols);
    float4 g1 = *(const float4*)(Bp + (size_t)kt*Ncols + 4);
    __syncthreads();
    As[lhalf*8+0][lr] = a0.x; As[lhalf*8+1][lr] = a0.y;
    As[lhalf*8+2][lr] = a0.z; As[lhalf*8+3][lr] = a0.w;
    As[lhalf*8+4][lr] = a1.x; As[lhalf*8+5][lr] = a1.y;
    As[lhalf*8+6][lr] = a1.z; As[lhalf*8+7][lr] = a1.w;
    *(float4*)&Bs[tid>>4][(tid&15)*8]     = g0;
    *(float4*)&Bs[tid>>4][(tid&15)*8 + 4] = g1;
    __syncthreads();
    #pragma unroll
    for (int k = 0; k < 16; k++){
      float4 av0 = *(float4*)&As[k][ty*8];
      float4 av1 = *(float4*)&As[k][ty*8+4];
      float4 bv0 = *(float4*)&Bs[k][tx*4];
      float4 bv1 = *(float4*)&Bs[k][64 + tx*4];
      float av[8] = {av0.x,av0.y,av0.z,av0.w,av1.x,av1.y,av1.z,av1.w};
      float bv[8] = {bv0.x,bv0.y,bv0.z,bv0.w,bv1.x,bv1.y,bv1.z,bv1.w};
      #pragma unroll
      for (int i = 0; i < 8; i++)
        #pragma unroll
        for (int j = 0; j < 8; j++)
          acc[i][j] = fmaf(av[i], bv[j], acc[i][j]);
    }
  }

  const int col0a = bx*128 + tx*4;
  const int col0b = col0a + 64;
  #pragma unroll
  for (int i = 0; i < 8; i++){
    int s = by*128 + ty*8 + i;
    float adda[4], addb[4];
    if (MODE == 1){
      int t = t_act[s], o = op_idx[s];
      float4 ia = *(const float4*)&idW[t*512 + col0a];
      float4 ib = *(const float4*)&idW[t*512 + col0b];
      float4 oa = *(const float4*)&opWb[o*512 + col0a];
      float4 ob = *(const float4*)&opWb[o*512 + col0b];
      adda[0]=ia.x+oa.x; adda[1]=ia.y+oa.y; adda[2]=ia.z+oa.z; adda[3]=ia.w+oa.w;
      addb[0]=ib.x+ob.x; addb[1]=ib.y+ob.y; addb[2]=ib.z+ob.z; addb[3]=ib.w+ob.w;
    } else {
      float4 ba = *(const float4*)&bias[col0a];
      float4 bb = *(const float4*)&bias[col0b];
      adda[0]=ba.x; adda[1]=ba.y; adda[2]=ba.z; adda[3]=ba.w;
      addb[0]=bb.x; addb[1]=bb.y; addb[2]=bb.z; addb[3]=bb.w;
    }
    float4 va, vb;
    float* pa = &va.x; float* pb = &vb.x;
    #pragma unroll
    for (int j = 0; j < 4; j++){
      float v0 = acc[i][j]   + adda[j];
      float v1 = acc[i][j+4] + addb[j];
      if (MODE != 2){ v0 = fmaxf(v0, 0.f); v1 = fmaxf(v1, 0.f); }
      pa[j] = v0; pb[j] = v1;
    }
    *(float4*)(C + (size_t)s*Ncols + col0a) = va;
    *(float4*)(C + (size_t)s*Ncols + col0b) = vb;
  }
}

__global__ __launch_bounds__(256)
void k_routeF(const float* __restrict__ h2, const float* __restrict__ Wr1,
              const float* __restrict__ Wr2, const float* __restrict__ br2,
              const float* __restrict__ tidWb,
              const int* __restrict__ t_act, const int* __restrict__ aidx,
              const int* __restrict__ meta, const uint32_t* __restrict__ keys, int hop,
              float* __restrict__ states, int* __restrict__ tempers, int* __restrict__ done){
  __shared__ float Wr1s[256][32];
  __shared__ float h2s[8][512];
  __shared__ float l32[8][32];

  const int tid = threadIdx.x;
  const int s0 = blockIdx.x * 8;

  for (int i4 = tid; i4 < 8*128; i4 += 256){
    int sl = i4 >> 7, q = i4 & 127;
    *(float4*)&h2s[sl][q*4] = *(const float4*)&h2[(size_t)(s0+sl)*512 + q*4];
  }

  const int lane = tid & 63, w = tid >> 6;
  const int half = lane >> 5, col = lane & 31;
  const int sl = w*2 + half;
  const int s  = s0 + sl;
  const int t  = t_act[s];
  float acc = tidWb[t*32 + col];

  for (int kh = 0; kh < 2; kh++){
    __syncthreads();
    for (int idx = tid; idx < 256*32; idx += 256)
      Wr1s[idx >> 5][idx & 31] = Wr1[kh*8192 + idx];
    __syncthreads();
    const int kb = kh * 256;
    #pragma unroll 4
    for (int k4 = 0; k4 < 64; k4++){
      float4 hv = *(float4*)&h2s[sl][kb + k4*4];
      acc = fmaf(hv.x, Wr1s[k4*4+0][col], acc);
      acc = fmaf(hv.y, Wr1s[k4*4+1][col], acc);
      acc = fmaf(hv.z, Wr1s[k4*4+2][col], acc);
      acc = fmaf(hv.w, Wr1s[k4*4+3][col], acc);
    }
  }
  l32[sl][col] = fmaxf(acc, 0.f);
  __syncthreads();

  const uint32_t sk0 = keys[4 + 4*hop], sk1 = keys[5 + 4*hop];
  int smp[2];
  for (int pass = 0; pass < 2; pass++){
    const int psl = w*2 + pass;
    const int ps  = s0 + psl;
    const int c = lane;
    float lg = br2[c];
    #pragma unroll
    for (int k = 0; k < 32; k++) lg = fmaf(l32[psl][k], Wr2[k*65 + c], lg);
    float lg64 = br2[64];
    #pragma unroll
    for (int k = 0; k < 32; k++) lg64 = fmaf(l32[psl][k], Wr2[k*65 + 64], lg64);
    float m = lg;
    for (int off = 32; off; off >>= 1) m = fmaxf(m, __shfl_xor(m, off));
    m = fmaxf(m, lg64);
    float se = expf(lg - m);
    for (int off = 32; off; off >>= 1) se += __shfl_xor(se, off);
    se += expf(lg64 - m);
    float Lse = logf(se);
    float g = jgumbel(jbits32(sk0, sk1, (uint32_t)(65*ps + c)));
    float v = (lg - m) - Lse + g;
    int idx = c;
    for (int off = 32; off; off >>= 1){
      float ov = __shfl_xor(v, off);
      int   oi = __shfl_xor(idx, off);
      if (ov > v || (ov == v && oi < idx)){ v = ov; idx = oi; }
    }
    float g64 = jgumbel(jbits32(sk0, sk1, (uint32_t)(65*ps + 64)));
    float v64 = (lg64 - m) - Lse + g64;
    if (v64 > v) idx = 64;
    smp[pass] = idx;
  }

  const int mysmp = smp[half];
  const int p = aidx[s];
  const int w0v = meta[1];
  const bool allowed = (p != 0) || (s == w0v);
  if (allowed){
    const float4* src = (const float4*)&h2s[sl][0];
    float4* dst = (float4*)(states + (size_t)p*512);
    for (int q = col; q < 128; q += 32) dst[q] = src[q];
    if (col == 0){
      tempers[p] = (mysmp < 63) ? mysmp : 63;
      done[p]    = (mysmp == 64) ? 1 : 0;
    }
  }
}

__global__ __launch_bounds__(256)
void k_latentF(const float* __restrict__ states, float* __restrict__ out){
  int idx = blockIdx.x*256 + threadIdx.x;
  int b = idx >> 9, j = idx & 511;
  float s = 0.f;
  #pragma unroll
  for (int u = 0; u < 16; u++) s += states[(size_t)(b*16 + u)*512 + j];
  out[idx] = s * 0.0625f;
}

// ------------------------------- launch ------------------------------------
extern "C" void kernel_launch(void* const* d_in, const int* in_sizes, int n_in,
                              void* d_out, int out_size, void* d_ws, size_t ws_size,
                              hipStream_t stream) {
  (void)in_sizes; (void)n_in; (void)out_size;
  const float* x         = (const float*)d_in[0];
  const float* op_emb    = (const float*)d_in[1];
  const float* op_logits = (const float*)d_in[2];
  const float* id_embeds = (const float*)d_in[3];
  const float* W1        = (const float*)d_in[4];
  const float* b1        = (const float*)d_in[5];
  const float* W2        = (const float*)d_in[6];
  const float* b2        = (const float*)d_in[7];
  const float* Wr1       = (const float*)d_in[8];
  const float* br1       = (const float*)d_in[9];
  const float* Wr2       = (const float*)d_in[10];
  const float* br2       = (const float*)d_in[11];
  const float* Wp        = (const float*)d_in[12];
  const float* bp        = (const float*)d_in[13];
  const float* tid_emb   = (const float*)d_in[14];
  const int*   seed      = (const int*)d_in[15];
  float* out = (float*)d_out;

  char* w = (char*)d_ws;
  uint32_t* keys = (uint32_t*)w;                 // @0
  float* logp3   = (float*)(w + 256);
  int*   meta    = (int*)(w + 512);
  int*   tempers = (int*)(w + 4096);
  int*   done    = tempers + NPATCH;
  int*   t_act   = done + NPATCH;
  int*   op_idx  = t_act + NPATCH;
  int*   aidx    = op_idx + NPATCH;
  float* idW     = (float*)(aidx + NPATCH);
  float* opWb    = idW + 64*512;
  float* tidWb   = opWb + 3*512;                 // ends < 1 MB

  const size_t SPh = (size_t)NPATCH*512;
  u16* W1T     = (u16*)(w + (1u<<20));           // 2 planes 512x512
  u16* W2T     = W1T + (size_t)2*512*512;        // 2 planes 512x512
  u16* Wr1P    = W2T + (size_t)2*512*512;        // 2 planes 32x512
  u16* WpT     = Wr1P + (size_t)2*32*512;        // 1 plane 8192x512
  u16* latP    = WpT + (size_t)8192*512;         // 1 plane 2048x512
  u16* statesP = latP + (size_t)2048*512;        // 2 planes
  u16* h1P     = statesP + 2*SPh;                // 2 planes
  float* l32g  = (float*)(h1P + 2*SPh);          // 32768 x 32 fp32
  const size_t NEED = (size_t)((char*)(l32g + (size_t)NPATCH*32) - w);

  k_keys<<<1, 64, 0, stream>>>(seed, op_logits, keys, logp3);
  k_init<<<NPATCH/256, 256, 0, stream>>>(keys, tempers, done);
  k_precomp<<<68, 256, 0, stream>>>(id_embeds, op_emb, tid_emb, W1, b1, Wr1, br1,
                                    idW, opWb, tidWb);

  if (ws_size >= NEED){
    // ---------------- fp16x2 MFMA path ----------------
    k_splitW<<<4624, 256, 0, stream>>>(W1, W2, Wp, Wr1, W1T, W2T, WpT, Wr1P);
    k_xsplit<<<(NPATCH*512/4)/256, 256, 0, stream>>>(x, statesP);

    for (int hop = 0; hop < NHOP; hop++){
      k_scan<<<1, 1024, 0, stream>>>(done, aidx, meta);
      k_gather<<<NPATCH/256, 256, 0, stream>>>(aidx, tempers, keys, logp3, hop, t_act, op_idx);
      k_mgemm<1,2><<<dim3(4, NPATCH/128), 256, 0, stream>>>(
          statesP, W1T, nullptr, h1P, aidx, nullptr, idW, opWb, t_act, op_idx, meta,
          512, SPh, (size_t)512*512, SPh);
      k_mgemm<3,2><<<dim3(4, NPATCH/128), 256, 0, stream>>>(
          h1P, W2T, nullptr, statesP, aidx, b2, nullptr, nullptr, nullptr, nullptr, meta,
          512, SPh, (size_t)512*512, SPh);
      k_routemm<<<NPATCH/64, 256, 0, stream>>>(statesP, Wr1P, aidx, t_act, tidWb, l32g);
      k_sample<<<NPATCH/8, 256, 0, stream>>>(l32g, Wr2, br2, aidx, meta, keys, hop,
                                             tempers, done);
    }

    k_latent2<<<(2048*512)/256, 256, 0, stream>>>(statesP, out, latP);
    k_mgemm<2,1><<<dim3(64, 16), 256, 0, stream>>>(
        latP, WpT, out + 2048*512, nullptr, nullptr, bp, nullptr, nullptr, nullptr, nullptr,
        nullptr, 8192, (size_t)2048*512, (size_t)8192*512, 0);
  } else {
    // ---------------- R1 fp32 fallback ----------------
    const size_t BIG0 = 2u<<20;
    const size_t SB   = (size_t)NPATCH * 512 * sizeof(float);
    float *states, *h1, *h2;
    bool copy_states;
    if (ws_size >= BIG0 + 3*SB){
      states = (float*)(w + BIG0);
      h1     = (float*)(w + BIG0 + SB);
      h2     = (float*)(w + BIG0 + 2*SB);
      copy_states = true;
    } else {
      states = (float*)d_in[0];
      h1     = (float*)(w + BIG0);
      h2     = (float*)(w + BIG0 + SB);
      copy_states = false;
    }
    if (copy_states)
      hipMemcpyAsync(states, x, SB, hipMemcpyDeviceToDevice, stream);

    for (int hop = 0; hop < NHOP; hop++){
      k_scan<<<1, 1024, 0, stream>>>(done, aidx, meta);
      k_gather<<<NPATCH/256, 256, 0, stream>>>(aidx, tempers, keys, logp3, hop, t_act, op_idx);
      k_gemmF<1><<<dim3(4, NPATCH/128), 256, 0, stream>>>(states, W1, h1, 512,
                                      aidx, nullptr, idW, opWb, t_act, op_idx);
      k_gemmF<0><<<dim3(4, NPATCH/128), 256, 0, stream>>>(h1, W2, h2, 512,
                                      nullptr, b2, nullptr, nullptr, nullptr, nullptr);
      k_routeF<<<NPATCH/8, 256, 0, stream>>>(h2, Wr1, Wr2, br2, tidWb, t_act, aidx,
                                      meta, keys, hop, states, tempers, done);
    }

    k_latentF<<<(2048*512)/256, 256, 0, stream>>>(states, out);
    k_gemmF<2><<<dim3(8192/128, 2048/128), 256, 0, stream>>>(out, Wp, out + 2048*512, 8192,
                                      nullptr, bp, nullptr, nullptr, nullptr, nullptr);
  }
}

// Round 2
// 985.697 us; speedup vs baseline: 1.0624x; 1.0085x over previous
//
#include <hip/hip_runtime.h>
#include <cstdint>
#include <cstddef>

// ---------------------------------------------------------------------------
// TemperGraph on gfx950 — R6: R5's MFMA GEMMs kept bit-identical. Small-kernel
// overhaul: k_routemm rewritten barrier-free (direct L2 gather fragments, same
// MFMA order -> bit-identical l32); k_scan split into 3 parallel kernels with
// k_gather fused; k_sample stages Wr2 in LDS. Exact JAX threefry preserved.
// ---------------------------------------------------------------------------

#define NPATCH 32768          // B(2048) * num_patches(16)
#define NHOP 4
#define RSCALE 4096.0f
#define RINV   2.44140625e-4f  // 2^-12

typedef unsigned short u16;
typedef __attribute__((ext_vector_type(8))) _Float16 half8;  // 8 f16 (4 VGPRs)
typedef __attribute__((ext_vector_type(4))) float f32x4;

#define GLDS(gp, lp) __builtin_amdgcn_global_load_lds( \
    (const __attribute__((address_space(1))) void*)(const void*)(gp), \
    (__attribute__((address_space(3))) void*)(void*)(lp), 16, 0, 0)

// ------------------------------- threefry ----------------------------------
__device__ __forceinline__ uint32_t rotl32(uint32_t x, int r){ return (x<<r)|(x>>(32-r)); }

__device__ __forceinline__ void tf2x32(uint32_t k0, uint32_t k1, uint32_t x0, uint32_t x1,
                                       uint32_t& o0, uint32_t& o1){
  uint32_t k2 = k0 ^ k1 ^ 0x1BD11BDAu;
  x0 += k0; x1 += k1;
#define TFR(r) { x0 += x1; x1 = rotl32(x1,(r)); x1 ^= x0; }
  TFR(13) TFR(15) TFR(26) TFR(6)   x0 += k1; x1 += k2 + 1u;
  TFR(17) TFR(29) TFR(16) TFR(24)  x0 += k2; x1 += k0 + 2u;
  TFR(13) TFR(15) TFR(26) TFR(6)   x0 += k0; x1 += k1 + 3u;
  TFR(17) TFR(29) TFR(16) TFR(24)  x0 += k1; x1 += k2 + 4u;
  TFR(13) TFR(15) TFR(26) TFR(6)   x0 += k2; x1 += k0 + 5u;
#undef TFR
  o0 = x0; o1 = x1;
}

__device__ __forceinline__ uint32_t jbits32(uint32_t k0, uint32_t k1, uint32_t idx){
  uint32_t a, b; tf2x32(k0, k1, 0u, idx, a, b);
  return a ^ b;
}

__device__ __forceinline__ void jsplit(uint32_t& r0, uint32_t& r1, uint32_t& c0, uint32_t& c1){
  uint32_t n0, n1;
  tf2x32(r0, r1, 0u, 0u, n0, n1);
  tf2x32(r0, r1, 0u, 1u, c0, c1);
  r0 = n0; r1 = n1;
}

__device__ __forceinline__ float jgumbel(uint32_t bits){
  float f = __uint_as_float(0x3f800000u | (bits >> 9)) - 1.0f;
  float u = fmaxf(f, 1.17549435e-38f);
  return -logf(-logf(u));
}

// ------------------------------- fp16 split helpers ------------------------
union uhcv { _Float16 h; u16 u; };
__device__ __forceinline__ u16 f2h(float x){ uhcv t; t.h = (_Float16)x; return t.u; }
__device__ __forceinline__ float h2f(u16 b){ uhcv t; t.u = b; return (float)t.h; }
__device__ __forceinline__ void split2s(float v, u16& a0, u16& a1){
  a0 = f2h(v);
  a1 = f2h((v - h2f(a0)) * RSCALE);
}

// ------------------------------- key derivation ----------------------------
__global__ void k_keys(const int* __restrict__ seed, const float* __restrict__ op_logits,
                       uint32_t* __restrict__ keys, float* __restrict__ logp3){
  if (threadIdx.x != 0 || blockIdx.x != 0) return;
  uint32_t r0 = 0u, r1 = (uint32_t)seed[0];
  uint32_t c0, c1;
  jsplit(r0, r1, c0, c1); keys[0] = c0; keys[1] = c1;          // tk
  for (int h = 0; h < NHOP; h++){
    jsplit(r0, r1, c0, c1); keys[2 + 4*h] = c0; keys[3 + 4*h] = c1;  // ok_h
    jsplit(r0, r1, c0, c1); keys[4 + 4*h] = c0; keys[5 + 4*h] = c1;  // sk_h
  }
  float l0 = op_logits[0], l1 = op_logits[1], l2 = op_logits[2];
  float mm = fmaxf(l0, fmaxf(l1, l2));
  float e0 = expf(l0-mm), e1 = expf(l1-mm), e2 = expf(l2-mm);
  float ssum = e0 + e1 + e2;
  logp3[0] = logf(e0/ssum); logp3[1] = logf(e1/ssum); logp3[2] = logf(e2/ssum);
}

// ------------------------------- init --------------------------------------
__global__ __launch_bounds__(256)
void k_init(const uint32_t* __restrict__ keys, int* __restrict__ tempers, int* __restrict__ done){
  int i = blockIdx.x*256 + threadIdx.x;
  uint32_t b = jbits32(keys[0], keys[1], (uint32_t)(NPATCH + i));
  tempers[i] = (int)(b & 63u);
  done[i] = 0;
}

// ------------------------------- precompute --------------------------------
__global__ __launch_bounds__(256)
void k_precomp(const float* __restrict__ id_embeds, const float* __restrict__ op_emb,
               const float* __restrict__ tid_emb,
               const float* __restrict__ W1, const float* __restrict__ b1,
               const float* __restrict__ Wr1, const float* __restrict__ br1,
               float* __restrict__ idW, float* __restrict__ opWb, float* __restrict__ tidWb){
  int b = blockIdx.x, tid = threadIdx.x;
  if (b < 64){
    for (int j = tid; j < 512; j += 256){
      float v = 0.f;
      #pragma unroll
      for (int u = 0; u < 4; u++) v = fmaf(id_embeds[b*4+u], W1[(size_t)(512+u)*512 + j], v);
      idW[b*512 + j] = v;
    }
  } else if (b < 67){
    int o = b - 64;
    for (int j = tid; j < 512; j += 256){
      float v = b1[j];
      for (int u = 0; u < 256; u++) v = fmaf(op_emb[o*256+u], W1[(size_t)(516+u)*512 + j], v);
      opWb[o*512 + j] = v;
    }
  } else {
    for (int idx = tid; idx < 2048; idx += 256){
      int t = idx >> 5, c = idx & 31;
      float v = br1[c];
      #pragma unroll
      for (int u = 0; u < 4; u++) v = fmaf(tid_emb[t*4+u], Wr1[(512+u)*32 + c], v);
      tidWb[idx] = v;
    }
  }
}

// ------------------------------- weight transpose + split ------------------
// W1T/W2T: 2 fp16 planes [512][512] (k contig). Wr1P: 2 planes [32][512].
// WpT: 1 plane [8192][512].
__global__ __launch_bounds__(256)
void k_splitW(const float* __restrict__ W1, const float* __restrict__ W2,
              const float* __restrict__ Wp, const float* __restrict__ Wr1,
              u16* __restrict__ W1T, u16* __restrict__ W2T, u16* __restrict__ WpT,
              u16* __restrict__ Wr1P){
  __shared__ float t[32][33];
  int blk = blockIdx.x;
  const float* src; u16* dst; int N; int deg; size_t pst; int tb;
  if (blk < 256){ src = W1; dst = W1T; N = 512; deg = 2; pst = (size_t)512*512; tb = blk; }
  else if (blk < 512){ src = W2; dst = W2T; N = 512; deg = 2; pst = (size_t)512*512; tb = blk - 256; }
  else if (blk < 528){ src = Wr1; dst = Wr1P; N = 32; deg = 2; pst = (size_t)32*512; tb = blk - 512; }
  else { src = Wp; dst = WpT; N = 8192; deg = 1; pst = 0; tb = blk - 528; }
  int n0 = (tb >> 4)*32, k0 = (tb & 15)*32;
  if (N == 32){ n0 = 0; k0 = tb*32; }
  int r = threadIdx.x >> 5, c = threadIdx.x & 31;
  for (int rr = r; rr < 32; rr += 8)
    t[rr][c] = src[(size_t)(k0+rr)*N + ((n0 + c) % N)];
  __syncthreads();
  for (int rr = r; rr < 32; rr += 8){
    if (n0 + rr >= N) break;
    float v = t[c][rr];                       // src[k0+c][n0+rr]
    size_t o = (size_t)(n0+rr)*512 + k0 + c;
    if (deg == 2){
      u16 a0, a1; split2s(v, a0, a1);
      dst[o] = a0; dst[pst + o] = a1;
    } else {
      dst[o] = f2h(v);
    }
  }
}

// ------------------------------- x -> states planes ------------------------
__global__ __launch_bounds__(256)
void k_xsplit(const float* __restrict__ x, u16* __restrict__ sP){
  size_t i = ((size_t)blockIdx.x*256 + threadIdx.x)*4;
  float4 v = *(const float4*)(x + i);
  ushort4 p0, p1;
  split2s(v.x, p0.x, p1.x); split2s(v.y, p0.y, p1.y);
  split2s(v.z, p0.z, p1.z); split2s(v.w, p0.w, p1.w);
  const size_t SP = (size_t)NPATCH*512;
  *(ushort4*)(sP + i) = p0; *(ushort4*)(sP + SP + i) = p1;
}

// ------------------------------- active compaction (hierarchical) ----------
// scan1: per-block inclusive scan of active flags; writes exclusive local
// prefix per element + per-block totals.
__global__ __launch_bounds__(1024)
void k_scan1(const int* __restrict__ done, int* __restrict__ lpref,
             int* __restrict__ partials){
  __shared__ int cnt[1024];
  const int tid = threadIdx.x;
  const int e = blockIdx.x*1024 + tid;
  int f = (done[e] == 0);
  cnt[tid] = f;
  __syncthreads();
  int val = f;
  for (int off = 1; off < 1024; off <<= 1){
    int v = (tid >= off) ? cnt[tid - off] : 0;
    __syncthreads();
    val += v; cnt[tid] = val;
    __syncthreads();
  }
  lpref[e] = val - f;                 // exclusive prefix within block
  if (tid == 1023) partials[blockIdx.x] = val;
}

// scan2: exclusive prefix of the 32 block totals (single wave) + meta.
__global__ void k_scan2(int* __restrict__ partials, int* __restrict__ meta){
  const int tid = threadIdx.x;        // 64 threads, lanes 0..31 active
  int f = (tid < 32) ? partials[tid] : 0;
  int v = f;
  #pragma unroll
  for (int off = 1; off < 32; off <<= 1){
    int u = __shfl_up(v, off);
    if (tid >= off) v += u;
  }
  if (tid < 32) partials[tid] = v - f;      // exclusive
  if (tid == 31){
    meta[0] = v;                            // na
    meta[1] = (v < NPATCH) ? (NPATCH - 1) : 0;
  }
}

// scan3: scatter compacted indices (stable ascending; done-fillers -> 0 at
// positions na..NPATCH-1, exactly as the old single-block scan), with the
// old k_gather fused (t_act + op sampling per slot).
__global__ __launch_bounds__(1024)
void k_scan3(const int* __restrict__ done, const int* __restrict__ lpref,
             const int* __restrict__ partials, const int* __restrict__ meta,
             const int* __restrict__ tempers,
             const uint32_t* __restrict__ keys, const float* __restrict__ logp3,
             int hop, int* __restrict__ aidx, int* __restrict__ t_act,
             int* __restrict__ op_idx){
  const int tid = threadIdx.x;
  const int e = blockIdx.x*1024 + tid;
  const int base = partials[blockIdx.x];
  const int lp = lpref[e];
  const int f = (done[e] == 0);
  const int na = meta[0];
  // #active before e = base + lp; #done before e = e - (base + lp)
  const int pos = f ? (base + lp) : (na + (e - base - lp));
  const int p = f ? e : 0;
  aidx[pos] = p;
  t_act[pos] = tempers[p];
  const uint32_t k0 = keys[2 + 4*hop], k1 = keys[3 + 4*hop];
  float best = 0.f; int bi = 0;
  #pragma unroll
  for (int c = 0; c < 3; c++){
    float v = jgumbel(jbits32(k0, k1, (uint32_t)(3*pos + c))) + logp3[c];
    if (c == 0 || v > best){ best = v; bi = c; }
  }
  op_idx[pos] = bi;
}

// ---------------- old single-block scan + gather (fp32 fallback path) ------
__global__ __launch_bounds__(1024)
void k_scan(const int* __restrict__ done, int* __restrict__ aidx, int* __restrict__ meta){
  __shared__ int cnt[1024];
  int tid = threadIdx.x;
  int base = tid * 32;
  unsigned flags = 0; int c = 0;
  #pragma unroll
  for (int i = 0; i < 32; i++){
    int f = (done[base + i] == 0);
    flags |= ((unsigned)f) << i;
    c += f;
  }
  cnt[tid] = c;
  __syncthreads();
  int val = c;
  for (int off = 1; off < 1024; off <<= 1){
    int v = (tid >= off) ? cnt[tid - off] : 0;
    __syncthreads();
    val += v; cnt[tid] = val;
    __syncthreads();
  }
  int pos = val - c;
  for (int i = 0; i < 32; i++){
    if ((flags >> i) & 1u) aidx[pos++] = base + i;
  }
  __syncthreads();
  int na = cnt[1023];
  for (int j = na + tid; j < NPATCH; j += 1024) aidx[j] = 0;
  if (tid == 0){
    meta[0] = na;
    meta[1] = (na < NPATCH) ? (NPATCH - 1) : 0;
  }
}

__global__ __launch_bounds__(256)
void k_gather(const int* __restrict__ aidx, const int* __restrict__ tempers,
              const uint32_t* __restrict__ keys, const float* __restrict__ logp3,
              int hop, int* __restrict__ t_act, int* __restrict__ op_idx){
  int s = blockIdx.x*256 + threadIdx.x;
  int p = aidx[s];
  t_act[s] = tempers[p];
  uint32_t k0 = keys[2 + 4*hop], k1 = keys[3 + 4*hop];
  float best = 0.f; int bi = 0;
  #pragma unroll
  for (int c = 0; c < 3; c++){
    float v = jgumbel(jbits32(k0, k1, (uint32_t)(3*s + c))) + logp3[c];
    if (c == 0 || v > best){ best = v; bi = c; }
  }
  op_idx[s] = bi;
}

// ------------------------------- fp16x2 MFMA GEMM --------------------------
// MODE 1: A gathered via aidx, + idW[t]+opWb[op], relu, write 2 planes (by s).
// MODE 3: + bias, relu, SCATTER 2 planes to outP[aidx[r]] masked last-wins.
// MODE 2: + bias, write fp32 (DEG=1).
// R5 structure kept verbatim: double-buffered LDS, counted vmcnt, raw
// s_barrier, setprio around MFMA, XCD block swizzle. Bit-identical math.
template<int MODE, int DEG>
__global__ __launch_bounds__(256, 2)
void k_mgemm(const u16* __restrict__ Ap, const u16* __restrict__ Bp,
             float* __restrict__ outF, u16* __restrict__ outP,
             const int* __restrict__ aidx, const float* __restrict__ bias,
             const float* __restrict__ idW, const float* __restrict__ opWb,
             const int* __restrict__ t_act, const int* __restrict__ op_idx,
             const int* __restrict__ meta,
             int Ncols, size_t aStride, size_t bStride, size_t oStride){
  __shared__ u16 As[2*DEG*4096];   // [dbuf][plane][128 rows][32 k, 16B-chunk swizzled]
  __shared__ u16 Bs[2*DEG*4096];
  const int tid = threadIdx.x;
  const int L = tid & 63, w = tid >> 6;

  const int gx = (int)gridDim.x;
  const int nwg = gx * (int)gridDim.y;
  int lin = (int)blockIdx.y * gx + (int)blockIdx.x;
  if ((nwg & 7) == 0)
    lin = (lin & 7) * (nwg >> 3) + (lin >> 3);
  const int m0 = (lin / gx) * 128, n0 = (lin % gx) * 128;
  const int wr = w >> 1, wc = w & 1;

  constexpr int SPW = DEG*4;
  constexpr int BUFO = DEG*4096;   // u16 elements per LDS buffer
  const bool isA = (w < 2);
  const u16* gB = isA ? Ap : Bp;
  u16* lB = isA ? As : Bs;
  const size_t pstride = isA ? aStride : bStride;
  const u16* gseg[8];
  u16* lseg[8];
  #pragma unroll
  for (int q = 0; q < SPW; q++){
    int ss = (w & 1)*SPW + q;
    int p = ss >> 3, rb = ss & 7;
    int row16 = rb*16 + (L >> 2);
    int grow;
    if (isA) grow = (MODE == 1) ? aidx[m0 + row16] : (m0 + row16);
    else     grow = n0 + row16;
    int swz = (L & 3) ^ ((L >> 2) & 3);
    gseg[q] = gB + p*pstride + (size_t)grow*512 + swz*8;
    lseg[q] = lB + p*4096 + rb*512;
  }

  f32x4 accM[4][4], accR[4][4];
  #pragma unroll
  for (int i = 0; i < 4; i++)
    #pragma unroll
    for (int j = 0; j < 4; j++){ accM[i][j] = (f32x4)0.f; accR[i][j] = (f32x4)0.f; }

  const int rdsw = ((L >> 4) ^ (L & 3))*8;
  const int frow = L & 15;

  // ---- prologue: stage K-tile 0 into buffer 0 ----
  #pragma unroll
  for (int q = 0; q < SPW; q++)
    GLDS(gseg[q], lseg[q]);

  #pragma unroll 2
  for (int kt = 0; kt < 16; kt++){
    const int cb = (kt & 1) * BUFO;
    if (kt < 15){
      const int nb = ((kt + 1) & 1) * BUFO;
      #pragma unroll
      for (int q = 0; q < SPW; q++)
        GLDS(gseg[q] + (kt+1)*32, lseg[q] + nb);
      // wait for OWN current-tile loads only; next tile's SPW stay in flight
      asm volatile("s_waitcnt vmcnt(%0)" :: "n"(SPW) : "memory");
    } else {
      asm volatile("s_waitcnt vmcnt(0)" ::: "memory");
    }
    __builtin_amdgcn_s_barrier();          // all waves' cur-tile LDS valid
    asm volatile("" ::: "memory");

    __builtin_amdgcn_s_setprio(1);
    #pragma unroll
    for (int pa = 0; pa < DEG; pa++){
      half8 af[4];
      #pragma unroll
      for (int i = 0; i < 4; i++)
        af[i] = *(const half8*)&As[cb + pa*4096 + (wr*64 + i*16 + frow)*32 + rdsw];
      #pragma unroll
      for (int pb = 0; pb < DEG - pa; pb++){
        #pragma unroll
        for (int j = 0; j < 4; j++){
          half8 bf = *(const half8*)&Bs[cb + pb*4096 + (wc*64 + j*16 + frow)*32 + rdsw];
          #pragma unroll
          for (int i = 0; i < 4; i++){
            if (pa + pb == 0)
              accM[i][j] = __builtin_amdgcn_mfma_f32_16x16x32_f16(af[i], bf, accM[i][j], 0, 0, 0);
            else
              accR[i][j] = __builtin_amdgcn_mfma_f32_16x16x32_f16(af[i], bf, accR[i][j], 0, 0, 0);
          }
        }
      }
    }
    __builtin_amdgcn_s_setprio(0);

    asm volatile("" ::: "memory");
    __builtin_amdgcn_s_barrier();          // all reads of cur buffer done ->
                                           // next iter may overwrite it
  }

  const int rbase = m0 + wr*64 + (L >> 4)*4;
  const int cbase = n0 + wc*64 + (L & 15);
  const int w0v = (MODE == 3) ? meta[1] : 0;
  #pragma unroll
  for (int i = 0; i < 4; i++){
    #pragma unroll
    for (int reg = 0; reg < 4; reg++){
      int r = rbase + i*16 + reg;
      if (MODE == 1){
        int t = t_act[r], o = op_idx[r];
        #pragma unroll
        for (int j = 0; j < 4; j++){
          int c = cbase + j*16;
          float v = accM[i][j][reg] + RINV*accR[i][j][reg] + idW[t*512 + c] + opWb[o*512 + c];
          v = fmaxf(v, 0.f);
          u16 a0, a1; split2s(v, a0, a1);
          size_t off = (size_t)r*512 + c;
          outP[off] = a0; outP[oStride + off] = a1;
        }
      } else if (MODE == 3){
        int p = aidx[r];
        bool allowed = (p != 0) || (r == w0v);
        #pragma unroll
        for (int j = 0; j < 4; j++){
          int c = cbase + j*16;
          float v = accM[i][j][reg] + RINV*accR[i][j][reg] + bias[c];
          v = fmaxf(v, 0.f);
          if (allowed){
            u16 a0, a1; split2s(v, a0, a1);
            size_t off = (size_t)p*512 + c;
            outP[off] = a0; outP[oStride + off] = a1;
          }
        }
      } else {
        #pragma unroll
        for (int j = 0; j < 4; j++){
          int c = cbase + j*16;
          float v = accM[i][j][reg] + bias[c];
          if (DEG == 2) v += RINV*accR[i][j][reg];
          outF[(size_t)r*Ncols + c] = v;
        }
      }
    }
  }
}

// ------------------------------- routing matvec via MFMA -------------------
// l32[s][c] = relu( statesP[aidx[s]] . Wr1P[c] + tidWb[t_act[s]][c] )
// R6: barrier-free. statesP/Wr1P are L2/L3-hot (just written / tiny); read
// A and B fragments DIRECTLY from global as 16B gathers. Fragment contents
// and MFMA order are bit-identical to the old LDS-staged version (verified
// lane-mapping identity), so l32 is bit-identical.
__global__ __launch_bounds__(256)
void k_routemm(const u16* __restrict__ sP, const u16* __restrict__ Wr1P,
               const int* __restrict__ aidx, const int* __restrict__ t_act,
               const float* __restrict__ tidWb, float* __restrict__ l32g){
  const int tid = threadIdx.x;
  const int L = tid & 63, w = tid >> 6;
  const int s0 = blockIdx.x*64 + w*16;            // this wave's 16 rows
  const size_t SPh = (size_t)NPATCH*512;

  // A: lane L holds row s0+(L&15), k-chunk (L>>4)*8
  const int arow = aidx[s0 + (L & 15)];
  const u16* a0p = sP + (size_t)arow*512 + (L >> 4)*8;
  const u16* a1p = a0p + SPh;
  // B: lane L holds col ct*16+(L&15), k-chunk (L>>4)*8, plane pb
  const u16* bb = Wr1P + (size_t)(L & 15)*512 + (L >> 4)*8;
  const size_t BPL = (size_t)32*512;              // plane stride
  const size_t BCT = (size_t)16*512;              // ct stride

  f32x4 accM[2], accR[2];
  accM[0] = (f32x4)0.f; accM[1] = (f32x4)0.f;
  accR[0] = (f32x4)0.f; accR[1] = (f32x4)0.f;

  #pragma unroll 4
  for (int kt = 0; kt < 16; kt++){
    const int ko = kt*32;
    half8 a0  = *(const half8*)(a0p + ko);
    half8 a1  = *(const half8*)(a1p + ko);
    half8 b00 = *(const half8*)(bb + ko);               // pl0 ct0
    half8 b01 = *(const half8*)(bb + BCT + ko);         // pl0 ct1
    half8 b10 = *(const half8*)(bb + BPL + ko);         // pl1 ct0
    half8 b11 = *(const half8*)(bb + BPL + BCT + ko);   // pl1 ct1
    // same order as old kernel: pa0/pb0 -> accM; pa0/pb1 -> accR; pa1/pb0 -> accR
    accM[0] = __builtin_amdgcn_mfma_f32_16x16x32_f16(a0, b00, accM[0], 0, 0, 0);
    accM[1] = __builtin_amdgcn_mfma_f32_16x16x32_f16(a0, b01, accM[1], 0, 0, 0);
    accR[0] = __builtin_amdgcn_mfma_f32_16x16x32_f16(a0, b10, accR[0], 0, 0, 0);
    accR[1] = __builtin_amdgcn_mfma_f32_16x16x32_f16(a0, b11, accR[1], 0, 0, 0);
    accR[0] = __builtin_amdgcn_mfma_f32_16x16x32_f16(a1, b00, accR[0], 0, 0, 0);
    accR[1] = __builtin_amdgcn_mfma_f32_16x16x32_f16(a1, b01, accR[1], 0, 0, 0);
  }

  #pragma unroll
  for (int reg = 0; reg < 4; reg++){
    int s = s0 + (L >> 4)*4 + reg;
    int t = t_act[s];
    #pragma unroll
    for (int ct = 0; ct < 2; ct++){
      int c = ct*16 + (L & 15);
      float v = accM[ct][reg] + RINV*accR[ct][reg] + tidWb[t*32 + c];
      l32g[(size_t)s*32 + c] = fmaxf(v, 0.f);
    }
  }
}

// ------------------------------- sampling ----------------------------------
__global__ __launch_bounds__(256)
void k_sample(const float* __restrict__ l32g, const float* __restrict__ Wr2,
              const float* __restrict__ br2,
              const int* __restrict__ aidx, const int* __restrict__ meta,
              const uint32_t* __restrict__ keys, int hop,
              int* __restrict__ tempers, int* __restrict__ done){
  __shared__ float l32s[8][32];
  __shared__ float Wr2s[32*65];                 // staged weights (same values)
  const int tid = threadIdx.x;
  const int s0 = blockIdx.x * 8;
  l32s[tid >> 5][tid & 31] = l32g[(size_t)s0*32 + tid];
  for (int i = tid; i < 32*65; i += 256) Wr2s[i] = Wr2[i];
  __syncthreads();

  const int lane = tid & 63, w = tid >> 6;
  const int half = lane >> 5;
  const uint32_t sk0 = keys[4 + 4*hop], sk1 = keys[5 + 4*hop];
  int smp[2];
  for (int pass = 0; pass < 2; pass++){
    const int psl = w*2 + pass;
    const int ps  = s0 + psl;
    const int c = lane;
    float lg = br2[c];
    #pragma unroll
    for (int k = 0; k < 32; k++) lg = fmaf(l32s[psl][k], Wr2s[k*65 + c], lg);
    float lg64 = br2[64];
    #pragma unroll
    for (int k = 0; k < 32; k++) lg64 = fmaf(l32s[psl][k], Wr2s[k*65 + 64], lg64);
    float m = lg;
    for (int off = 32; off; off >>= 1) m = fmaxf(m, __shfl_xor(m, off));
    m = fmaxf(m, lg64);
    float se = expf(lg - m);
    for (int off = 32; off; off >>= 1) se += __shfl_xor(se, off);
    se += expf(lg64 - m);
    float Lse = logf(se);
    float g = jgumbel(jbits32(sk0, sk1, (uint32_t)(65*ps + c)));
    float v = (lg - m) - Lse + g;
    int idx = c;
    for (int off = 32; off; off >>= 1){
      float ov = __shfl_xor(v, off);
      int   oi = __shfl_xor(idx, off);
      if (ov > v || (ov == v && oi < idx)){ v = ov; idx = oi; }
    }
    float g64 = jgumbel(jbits32(sk0, sk1, (uint32_t)(65*ps + 64)));
    float v64 = (lg64 - m) - Lse + g64;
    if (v64 > v) idx = 64;
    smp[pass] = idx;
  }

  const int s = s0 + w*2 + half;
  const int mysmp = smp[half];
  const int p = aidx[s];
  const bool allowed = (p != 0) || (s == meta[1]);
  if (allowed && (lane & 31) == 0){
    tempers[p] = (mysmp < 63) ? mysmp : 63;
    done[p]    = (mysmp == 64) ? 1 : 0;
  }
}

// ------------------------------- latent (mean over patches) ----------------
__global__ __launch_bounds__(256)
void k_latent2(const u16* __restrict__ sP, float* __restrict__ outF, u16* __restrict__ latP){
  int idx = blockIdx.x*256 + threadIdx.x;       // < 2048*512
  int b = idx >> 9, j = idx & 511;
  const size_t SP = (size_t)NPATCH*512;
  float s = 0.f;
  #pragma unroll 4
  for (int u = 0; u < 16; u++){
    size_t e = (size_t)(b*16 + u)*512 + j;
    s += h2f(sP[e]) + RINV*h2f(sP[SP + e]);
  }
  s *= 0.0625f;
  outF[idx] = s;
  latP[idx] = f2h(s);
}

// ===========================================================================
// ------------- R1 fallback pipeline (fp32 VALU GEMM), verbatim -------------
// ===========================================================================
template<int MODE>
__global__ __launch_bounds__(256)
void k_gemmF(const float* __restrict__ A, const float* __restrict__ B, float* __restrict__ C,
             int Ncols,
             const int* __restrict__ aidx,
             const float* __restrict__ bias,
             const float* __restrict__ idW, const float* __restrict__ opWb,
             const int* __restrict__ t_act, const int* __restrict__ op_idx){
  __shared__ float As[16][128];
  __shared__ float Bs[16][128];
  const int tid = threadIdx.x;
  const int bx = blockIdx.x, by = blockIdx.y;
  const int tx = tid & 15, ty = tid >> 4;
  const int lr = tid >> 1, lhalf = tid & 1;
  const int srow = by*128 + lr;
  const int arow = (MODE == 1) ? aidx[srow] : srow;
  const float* Ap = A + (size_t)arow*512 + lhalf*8;
  const float* Bp = B + (size_t)(tid >> 4)*Ncols + bx*128 + (tid & 15)*8;

  float acc[8][8];
  #pragma unroll
  for (int i = 0; i < 8; i++)
    #pragma unroll
    for (int j = 0; j < 8; j++) acc[i][j] = 0.f;

  for (int kt = 0; kt < 512; kt += 16){
    float4 a0 = *(const float4*)(Ap + kt);
    float4 a1 = *(const float4*)(Ap + kt + 4);
    float4 g0 = *(const float4*)(Bp + (size_t)kt*Ncols);
    float4 g1 = *(const float4*)(Bp + (size_t)kt*Ncols + 4);
    __syncthreads();
    As[lhalf*8+0][lr] = a0.x; As[lhalf*8+1][lr] = a0.y;
    As[lhalf*8+2][lr] = a0.z; As[lhalf*8+3][lr] = a0.w;
    As[lhalf*8+4][lr] = a1.x; As[lhalf*8+5][lr] = a1.y;
    As[lhalf*8+6][lr] = a1.z; As[lhalf*8+7][lr] = a1.w;
    *(float4*)&Bs[tid>>4][(tid&15)*8]     = g0;
    *(float4*)&Bs[tid>>4][(tid&15)*8 + 4] = g1;
    __syncthreads();
    #pragma unroll
    for (int k = 0; k < 16; k++){
      float4 av0 = *(float4*)&As[k][ty*8];
      float4 av1 = *(float4*)&As[k][ty*8+4];
      float4 bv0 = *(float4*)&Bs[k][tx*4];
      float4 bv1 = *(float4*)&Bs[k][64 + tx*4];
      float av[8] = {av0.x,av0.y,av0.z,av0.w,av1.x,av1.y,av1.z,av1.w};
      float bv[8] = {bv0.x,bv0.y,bv0.z,bv0.w,bv1.x,bv1.y,bv1.z,bv1.w};
      #pragma unroll
      for (int i = 0; i < 8; i++)
        #pragma unroll
        for (int j = 0; j < 8; j++)
          acc[i][j] = fmaf(av[i], bv[j], acc[i][j]);
    }
  }

  const int col0a = bx*128 + tx*4;
  const int col0b = col0a + 64;
  #pragma unroll
  for (int i = 0; i < 8; i++){
    int s = by*128 + ty*8 + i;
    float adda[4], addb[4];
    if (MODE == 1){
      int t = t_act[s], o = op_idx[s];
      float4 ia = *(const float4*)&idW[t*512 + col0a];
      float4 ib = *(const float4*)&idW[t*512 + col0b];
      float4 oa = *(const float4*)&opWb[o*512 + col0a];
      float4 ob = *(const float4*)&opWb[o*512 + col0b];
      adda[0]=ia.x+oa.x; adda[1]=ia.y+oa.y; adda[2]=ia.z+oa.z; adda[3]=ia.w+oa.w;
      addb[0]=ib.x+ob.x; addb[1]=ib.y+ob.y; addb[2]=ib.z+ob.z; addb[3]=ib.w+ob.w;
    } else {
      float4 ba = *(const float4*)&bias[col0a];
      float4 bb = *(const float4*)&bias[col0b];
      adda[0]=ba.x; adda[1]=ba.y; adda[2]=ba.z; adda[3]=ba.w;
      addb[0]=bb.x; addb[1]=bb.y; addb[2]=bb.z; addb[3]=bb.w;
    }
    float4 va, vb;
    float* pa = &va.x; float* pb = &vb.x;
    #pragma unroll
    for (int j = 0; j < 4; j++){
      float v0 = acc[i][j]   + adda[j];
      float v1 = acc[i][j+4] + addb[j];
      if (MODE != 2){ v0 = fmaxf(v0, 0.f); v1 = fmaxf(v1, 0.f); }
      pa[j] = v0; pb[j] = v1;
    }
    *(float4*)(C + (size_t)s*Ncols + col0a) = va;
    *(float4*)(C + (size_t)s*Ncols + col0b) = vb;
  }
}

__global__ __launch_bounds__(256)
void k_routeF(const float* __restrict__ h2, const float* __restrict__ Wr1,
              const float* __restrict__ Wr2, const float* __restrict__ br2,
              const float* __restrict__ tidWb,
              const int* __restrict__ t_act, const int* __restrict__ aidx,
              const int* __restrict__ meta, const uint32_t* __restrict__ keys, int hop,
              float* __restrict__ states, int* __restrict__ tempers, int* __restrict__ done){
  __shared__ float Wr1s[256][32];
  __shared__ float h2s[8][512];
  __shared__ float l32[8][32];

  const int tid = threadIdx.x;
  const int s0 = blockIdx.x * 8;

  for (int i4 = tid; i4 < 8*128; i4 += 256){
    int sl = i4 >> 7, q = i4 & 127;
    *(float4*)&h2s[sl][q*4] = *(const float4*)&h2[(size_t)(s0+sl)*512 + q*4];
  }

  const int lane = tid & 63, w = tid >> 6;
  const int half = lane >> 5, col = lane & 31;
  const int sl = w*2 + half;
  const int s  = s0 + sl;
  const int t  = t_act[s];
  float acc = tidWb[t*32 + col];

  for (int kh = 0; kh < 2; kh++){
    __syncthreads();
    for (int idx = tid; idx < 256*32; idx += 256)
      Wr1s[idx >> 5][idx & 31] = Wr1[kh*8192 + idx];
    __syncthreads();
    const int kb = kh * 256;
    #pragma unroll 4
    for (int k4 = 0; k4 < 64; k4++){
      float4 hv = *(float4*)&h2s[sl][kb + k4*4];
      acc = fmaf(hv.x, Wr1s[k4*4+0][col], acc);
      acc = fmaf(hv.y, Wr1s[k4*4+1][col], acc);
      acc = fmaf(hv.z, Wr1s[k4*4+2][col], acc);
      acc = fmaf(hv.w, Wr1s[k4*4+3][col], acc);
    }
  }
  l32[sl][col] = fmaxf(acc, 0.f);
  __syncthreads();

  const uint32_t sk0 = keys[4 + 4*hop], sk1 = keys[5 + 4*hop];
  int smp[2];
  for (int pass = 0; pass < 2; pass++){
    const int psl = w*2 + pass;
    const int ps  = s0 + psl;
    const int c = lane;
    float lg = br2[c];
    #pragma unroll
    for (int k = 0; k < 32; k++) lg = fmaf(l32[psl][k], Wr2[k*65 + c], lg);
    float lg64 = br2[64];
    #pragma unroll
    for (int k = 0; k < 32; k++) lg64 = fmaf(l32[psl][k], Wr2[k*65 + 64], lg64);
    float m = lg;
    for (int off = 32; off; off >>= 1) m = fmaxf(m, __shfl_xor(m, off));
    m = fmaxf(m, lg64);
    float se = expf(lg - m);
    for (int off = 32; off; off >>= 1) se += __shfl_xor(se, off);
    se += expf(lg64 - m);
    float Lse = logf(se);
    float g = jgumbel(jbits32(sk0, sk1, (uint32_t)(65*ps + c)));
    float v = (lg - m) - Lse + g;
    int idx = c;
    for (int off = 32; off; off >>= 1){
      float ov = __shfl_xor(v, off);
      int   oi = __shfl_xor(idx, off);
      if (ov > v || (ov == v && oi < idx)){ v = ov; idx = oi; }
    }
    float g64 = jgumbel(jbits32(sk0, sk1, (uint32_t)(65*ps + 64)));
    float v64 = (lg64 - m) - Lse + g64;
    if (v64 > v) idx = 64;
    smp[pass] = idx;
  }

  const int mysmp = smp[half];
  const int p = aidx[s];
  const int w0v = meta[1];
  const bool allowed = (p != 0) || (s == w0v);
  if (allowed){
    const float4* src = (const float4*)&h2s[sl][0];
    float4* dst = (float4*)(states + (size_t)p*512);
    for (int q = col; q < 128; q += 32) dst[q] = src[q];
    if (col == 0){
      tempers[p] = (mysmp < 63) ? mysmp : 63;
      done[p]    = (mysmp == 64) ? 1 : 0;
    }
  }
}

__global__ __launch_bounds__(256)
void k_latentF(const float* __restrict__ states, float* __restrict__ out){
  int idx = blockIdx.x*256 + threadIdx.x;
  int b = idx >> 9, j = idx & 511;
  float s = 0.f;
  #pragma unroll
  for (int u = 0; u < 16; u++) s += states[(size_t)(b*16 + u)*512 + j];
  out[idx] = s * 0.0625f;
}

// ------------------------------- launch ------------------------------------
extern "C" void kernel_launch(void* const* d_in, const int* in_sizes, int n_in,
                              void* d_out, int out_size, void* d_ws, size_t ws_size,
                              hipStream_t stream) {
  (void)in_sizes; (void)n_in; (void)out_size;
  const float* x         = (const float*)d_in[0];
  const float* op_emb    = (const float*)d_in[1];
  const float* op_logits = (const float*)d_in[2];
  const float* id_embeds = (const float*)d_in[3];
  const float* W1        = (const float*)d_in[4];
  const float* b1        = (const float*)d_in[5];
  const float* W2        = (const float*)d_in[6];
  const float* b2        = (const float*)d_in[7];
  const float* Wr1       = (const float*)d_in[8];
  const float* br1       = (const float*)d_in[9];
  const float* Wr2       = (const float*)d_in[10];
  const float* br2       = (const float*)d_in[11];
  const float* Wp        = (const float*)d_in[12];
  const float* bp        = (const float*)d_in[13];
  const float* tid_emb   = (const float*)d_in[14];
  const int*   seed      = (const int*)d_in[15];
  float* out = (float*)d_out;

  char* w = (char*)d_ws;
  uint32_t* keys = (uint32_t*)w;                 // @0
  float* logp3   = (float*)(w + 256);
  int*   meta    = (int*)(w + 512);
  int*   tempers = (int*)(w + 4096);
  int*   done    = tempers + NPATCH;
  int*   t_act   = done + NPATCH;
  int*   op_idx  = t_act + NPATCH;
  int*   aidx    = op_idx + NPATCH;
  int*   lpref   = aidx + NPATCH;
  float* idW     = (float*)(lpref + NPATCH);
  float* opWb    = idW + 64*512;
  float* tidWb   = opWb + 3*512;
  int*   partials= (int*)(tidWb + 2048);         // 32 ints; ends < 1 MB

  const size_t SPh = (size_t)NPATCH*512;
  u16* W1T     = (u16*)(w + (1u<<20));           // 2 planes 512x512
  u16* W2T     = W1T + (size_t)2*512*512;        // 2 planes 512x512
  u16* Wr1P    = W2T + (size_t)2*512*512;        // 2 planes 32x512
  u16* WpT     = Wr1P + (size_t)2*32*512;        // 1 plane 8192x512
  u16* latP    = WpT + (size_t)8192*512;         // 1 plane 2048x512
  u16* statesP = latP + (size_t)2048*512;        // 2 planes
  u16* h1P     = statesP + 2*SPh;                // 2 planes
  float* l32g  = (float*)(h1P + 2*SPh);          // 32768 x 32 fp32
  const size_t NEED = (size_t)((char*)(l32g + (size_t)NPATCH*32) - w);

  k_keys<<<1, 64, 0, stream>>>(seed, op_logits, keys, logp3);
  k_init<<<NPATCH/256, 256, 0, stream>>>(keys, tempers, done);
  k_precomp<<<68, 256, 0, stream>>>(id_embeds, op_emb, tid_emb, W1, b1, Wr1, br1,
                                    idW, opWb, tidWb);

  if (ws_size >= NEED){
    // ---------------- fp16x2 MFMA path ----------------
    k_splitW<<<4624, 256, 0, stream>>>(W1, W2, Wp, Wr1, W1T, W2T, WpT, Wr1P);
    k_xsplit<<<(NPATCH*512/4)/256, 256, 0, stream>>>(x, statesP);

    for (int hop = 0; hop < NHOP; hop++){
      k_scan1<<<NPATCH/1024, 1024, 0, stream>>>(done, lpref, partials);
      k_scan2<<<1, 64, 0, stream>>>(partials, meta);
      k_scan3<<<NPATCH/1024, 1024, 0, stream>>>(done, lpref, partials, meta,
                                                tempers, keys, logp3, hop,
                                                aidx, t_act, op_idx);
      k_mgemm<1,2><<<dim3(4, NPATCH/128), 256, 0, stream>>>(
          statesP, W1T, nullptr, h1P, aidx, nullptr, idW, opWb, t_act, op_idx, meta,
          512, SPh, (size_t)512*512, SPh);
      k_mgemm<3,2><<<dim3(4, NPATCH/128), 256, 0, stream>>>(
          h1P, W2T, nullptr, statesP, aidx, b2, nullptr, nullptr, nullptr, nullptr, meta,
          512, SPh, (size_t)512*512, SPh);
      k_routemm<<<NPATCH/64, 256, 0, stream>>>(statesP, Wr1P, aidx, t_act, tidWb, l32g);
      k_sample<<<NPATCH/8, 256, 0, stream>>>(l32g, Wr2, br2, aidx, meta, keys, hop,
                                             tempers, done);
    }

    k_latent2<<<(2048*512)/256, 256, 0, stream>>>(statesP, out, latP);
    k_mgemm<2,1><<<dim3(64, 16), 256, 0, stream>>>(
        latP, WpT, out + 2048*512, nullptr, nullptr, bp, nullptr, nullptr, nullptr, nullptr,
        nullptr, 8192, (size_t)2048*512, (size_t)8192*512, 0);
  } else {
    // ---------------- R1 fp32 fallback ----------------
    const size_t BIG0 = 2u<<20;
    const size_t SB   = (size_t)NPATCH * 512 * sizeof(float);
    float *states, *h1, *h2;
    bool copy_states;
    if (ws_size >= BIG0 + 3*SB){
      states = (float*)(w + BIG0);
      h1     = (float*)(w + BIG0 + SB);
      h2     = (float*)(w + BIG0 + 2*SB);
      copy_states = true;
    } else {
      states = (float*)d_in[0];
      h1     = (float*)(w + BIG0);
      h2     = (float*)(w + BIG0 + SB);
      copy_states = false;
    }
    if (copy_states)
      hipMemcpyAsync(states, x, SB, hipMemcpyDeviceToDevice, stream);

    for (int hop = 0; hop < NHOP; hop++){
      k_scan<<<1, 1024, 0, stream>>>(done, aidx, meta);
      k_gather<<<NPATCH/256, 256, 0, stream>>>(aidx, tempers, keys, logp3, hop, t_act, op_idx);
      k_gemmF<1><<<dim3(4, NPATCH/128), 256, 0, stream>>>(states, W1, h1, 512,
                                      aidx, nullptr, idW, opWb, t_act, op_idx);
      k_gemmF<0><<<dim3(4, NPATCH/128), 256, 0, stream>>>(h1, W2, h2, 512,
                                      nullptr, b2, nullptr, nullptr, nullptr, nullptr);
      k_routeF<<<NPATCH/8, 256, 0, stream>>>(h2, Wr1, Wr2, br2, tidWb, t_act, aidx,
                                      meta, keys, hop, states, tempers, done);
    }

    k_latentF<<<(2048*512)/256, 256, 0, stream>>>(states, out);
    k_gemmF<2><<<dim3(8192/128, 2048/128), 256, 0, stream>>>(out, Wp, out + 2048*512, 8192,
                                      nullptr, bp, nullptr, nullptr, nullptr, nullptr);
  }
}